// Round 12
// baseline (941.001 us; speedup 1.0000x reference)
//
#include <hip/hip_runtime.h>
#include <stdint.h>

#define NE 500000
#define NN 50000
#define ND 256
#define ED 128
#define GD 64
#define MAXDEG 64
#define NB 392            // row buckets (50000/128 = 391, padded to %8)
#define BCAP 2048         // bucket capacity: mean 1280, sigma 36 -> +21 sigma

typedef float f4v __attribute__((ext_vector_type(4)));
typedef short s8v __attribute__((ext_vector_type(8)));
typedef short s4v __attribute__((ext_vector_type(4)));

static __device__ __forceinline__ short f2bf(float f) {
  union { float f; uint32_t u; } v; v.f = f;
  uint32_t r = v.u + 0x7FFFu + ((v.u >> 16) & 1u);
  return (short)(r >> 16);
}
static __device__ __forceinline__ float bf2f(uint32_t u) {
  union { uint32_t u; float f; } v; v.u = u << 16; return v.f;
}

// ---- convert fp32 -> bf16 (vectorized x4) ----
__global__ void cvt_bf16_kernel(const float* __restrict__ src, short* __restrict__ dst, int n) {
  int i = (blockIdx.x * blockDim.x + threadIdx.x) * 4;
  if (i >= n) return;
  const float4 v = *(const float4*)(src + i);
  s4v o; o[0] = f2bf(v.x); o[1] = f2bf(v.y); o[2] = f2bf(v.z); o[3] = f2bf(v.w);
  *(s4v*)(dst + i) = o;
}

// ---- pack W[K][C] fp32 -> bf16 MFMA fragment order [ks][c][kh][j] ----
static __device__ __forceinline__ void pack_one(const float* src, short* dst, int C, int idx) {
  int k = idx / C, c = idx - k * C;
  int ks = k >> 5, kh = (k >> 3) & 3, j = k & 7;
  dst[(((ks * C + c) * 4 + kh) << 3) + j] = f2bf(src[idx]);
}

// ---- single fused pack kernel for all 5 weight packs ----
#define S1 131072   // w1xp: W1 rows 0..255   (256x512)
#define S2 65536    // w1ep: W1 rows 256..383 (128x512)
#define S3 65536    // w2p  (512x128)
#define S4 458752   // w3p  (448x1024)
#define S5 262144   // w4p  (1024x256)
__global__ void pack_all_kernel(const float* __restrict__ W1, const float* __restrict__ W2,
                                const float* __restrict__ W3, const float* __restrict__ W4,
                                short* __restrict__ w1xp, short* __restrict__ w1ep,
                                short* __restrict__ w2p, short* __restrict__ w3p,
                                short* __restrict__ w4p) {
  int idx = blockIdx.x * blockDim.x + threadIdx.x;
  if (idx < S1) { pack_one(W1, w1xp, 512, idx); return; }
  idx -= S1;
  if (idx < S2) { pack_one(W1 + 256 * 512, w1ep, 512, idx); return; }
  idx -= S2;
  if (idx < S3) { pack_one(W2, w2p, 128, idx); return; }
  idx -= S3;
  if (idx < S4) { pack_one(W3, w3p, 1024, idx); return; }
  idx -= S4;
  if (idx < S5) { pack_one(W4, w4p, 256, idx); return; }
}

// fallback single pack (w1p full-K, no-hx path)
__global__ void pack_w_kernel(const float* __restrict__ src, short* __restrict__ dst, int K, int C) {
  int idx = blockIdx.x * blockDim.x + threadIdx.x;
  if (idx >= K * C) return;
  pack_one(src, dst, C, idx);
}

// ---- single-pass bucket build (row-window sort) + per-dest elist ----
__global__ void bucket_build_kernel(const int* __restrict__ erow, const int* __restrict__ ecol,
                                    unsigned int* __restrict__ bcnt, int* __restrict__ bucket,
                                    unsigned int* __restrict__ cnt, int* __restrict__ elist) {
  int e = blockIdx.x * blockDim.x + threadIdx.x;
  if (e >= NE) return;
  int r = erow[e];
  int b = r >> 7;
  unsigned int s = atomicAdd(&bcnt[b], 1u);
  if (s < BCAP) bucket[b * BCAP + s] = e;
  int c = ecol[e];
  unsigned int k = atomicAdd(&cnt[c], 1u);
  if (k < MAXDEG) elist[c * MAXDEG + k] = e;
}

// ---- build per-destination lists only (fallback path) ----
__global__ void build_kernel(const int* __restrict__ ecol, unsigned int* __restrict__ cnt,
                             int* __restrict__ elist) {
  int e = blockIdx.x * blockDim.x + threadIdx.x;
  if (e >= NE) return;
  int c = ecol[e];
  unsigned int slot = atomicAdd(&cnt[c], 1u);
  if (slot < MAXDEG) elist[c * MAXDEG + slot] = e;
}

// ---- gather-mean: one wave per node, lane handles 2 dims (ebuf by eid) ----
__global__ void agg_kernel(const unsigned short* __restrict__ ebuf,
                           const int* __restrict__ elist,
                           const unsigned int* __restrict__ cnt,
                           unsigned short* __restrict__ aggbf) {
  int tid = threadIdx.x;
  int lane = tid & 63;
  int node = blockIdx.x * 4 + (tid >> 6);
  if (node >= NN) return;
  unsigned int deg = cnt[node];
  unsigned int jend = deg < MAXDEG ? deg : MAXDEG;
  float a0 = 0.f, a1 = 0.f;
  const int* el = elist + (size_t)node * MAXDEG;
  for (unsigned int j = 0; j < jend; ++j) {
    int eid = el[j];
    uint32_t v = *(const uint32_t*)(ebuf + (size_t)eid * ED + 2 * lane);
    a0 += bf2f(v & 0xFFFFu);
    a1 += bf2f(v >> 16);
  }
  float rc = 1.0f / (deg > 0 ? (float)deg : 1.0f);
  uint32_t o = (uint32_t)(uint16_t)f2bf(a0 * rc) | ((uint32_t)(uint16_t)f2bf(a1 * rc) << 16);
  *(uint32_t*)(aggbf + (size_t)node * ED + 2 * lane) = o;
}

// =======================================================================
// hx kernel: hx[50K][512] = xbf @ W1[0:256,:]
// =======================================================================
__launch_bounds__(512, 4)
__global__ void hx_kernel(const short* __restrict__ xbf,
                          const short* __restrict__ w1xp,
                          short* __restrict__ hx) {
  __shared__ __align__(16) short smem[64 * 256];
  const int tid = threadIdx.x;
  const int lane = tid & 63;
  const int w = tid >> 6;
  const int lh = lane >> 4;
  const int ll = lane & 15;
  const int n0 = blockIdx.x * 64;

  #pragma unroll
  for (int it = 0; it < 4; ++it) {
    int ch = tid + it * 512;
    int rr = ch >> 5, cc = (ch & 31) * 8;
    s8v vals = {0, 0, 0, 0, 0, 0, 0, 0};
    if (n0 + rr < NN) vals = *(const s8v*)(xbf + (size_t)(n0 + rr) * ND + cc);
    int byte = (rr * 512 + cc * 2) ^ ((rr & 7) << 4);
    *(s8v*)((char*)smem + byte) = vals;
  }
  __syncthreads();

  f4v acc[4][4];
  #pragma unroll
  for (int n = 0; n < 4; ++n)
    #pragma unroll
    for (int m = 0; m < 4; ++m)
      acc[n][m] = (f4v){0.f, 0.f, 0.f, 0.f};

  for (int ks = 0; ks < 8; ++ks) {
    s8v hf[4];
    #pragma unroll
    for (int m = 0; m < 4; ++m) {
      int row = 16 * m + ll;
      int byte = (row * 512 + ks * 64 + lh * 16) ^ ((row & 7) << 4);
      hf[m] = *(const s8v*)((const char*)smem + byte);
    }
    #pragma unroll
    for (int n = 0; n < 4; ++n) {
      s8v wf = *(const s8v*)(w1xp + (((ks * 512 + w * 64 + 16 * n + ll) * 4 + lh) << 3));
      #pragma unroll
      for (int m = 0; m < 4; ++m)
        acc[n][m] = __builtin_amdgcn_mfma_f32_16x16x32_bf16(wf, hf[m], acc[n][m], 0, 0, 0);
    }
  }

  #pragma unroll
  for (int n = 0; n < 4; ++n) {
    int cb = w * 64 + 16 * n + 4 * lh;
    #pragma unroll
    for (int m = 0; m < 4; ++m) {
      int node = n0 + 16 * m + ll;
      if (node < NN) {
        s4v o;
        o[0] = f2bf(acc[n][m][0]);
        o[1] = f2bf(acc[n][m][1]);
        o[2] = f2bf(acc[n][m][2]);
        o[3] = f2bf(acc[n][m][3]);
        *(s4v*)(hx + (size_t)node * 512 + cb) = o;
      }
    }
  }
}

// =======================================================================
// Edge kernel (HX + ROW-BUCKETS): tile t of bucket b handles slots
// [t*128, t*128+128) of bucket[b]. XCD-gathering swizzle: bucket b -> XCD
// b%8 so the bucket's 128-row hx slab (128KB) stays hot in that XCD's L2.
// GEMM1 = ea@W1e (K=128); hx[erow[eid]] read from GLOBAL in H1 epilogue
// only (no cross-phase reg holds -> no spill). Full H1 [128][512], GEMM2
// K=512. ebuf indexed by raw eid (R10-proven agg path).
// =======================================================================
__launch_bounds__(1024, 4)
__global__ void edge_hx_kernel(const short* __restrict__ hx,
                               const float* __restrict__ edge_attr,
                               const short* __restrict__ w1ep,
                               const float* __restrict__ b1,
                               const short* __restrict__ w2p,
                               const float* __restrict__ b2,
                               const int* __restrict__ erow,
                               const int* __restrict__ bucket,
                               const unsigned int* __restrict__ bcnt,
                               unsigned short* __restrict__ ebuf) {
  __shared__ __align__(16) short smem[128 * 128 + 128 * 512];  // 32KB ea/out + 128KB H1
  char* const h1b = (char*)(smem + 128 * 128);
  const int tid = threadIdx.x;
  const int lane = tid & 63;
  const int w = tid >> 6;          // 0..15
  const int lh = lane >> 4;        // 0..3
  const int ll = lane & 15;        // 0..15

  // ---- bucket/tile from XCD-gathering swizzle ----
  const int bid = blockIdx.x;                 // 0 .. NB*16-1
  const int b = ((bid >> 3) >> 4) * 8 + (bid & 7);
  const int t = (bid >> 3) & 15;
  unsigned int fill = bcnt[b]; if (fill > (unsigned)BCAP) fill = BCAP;
  int navail = (int)fill - t * 128;
  if (navail <= 0) return;
  if (navail > 128) navail = 128;
  const int base = b * BCAP + t * 128;

  // ---- stage ea tile [128][128] bf16 swizzled ----
  #pragma unroll
  for (int it = 0; it < 2; ++it) {
    int ch = tid + it * 1024;            // 2048 chunks of 8 elems
    int rr = ch >> 4;
    int cc = (ch & 15) * 8;
    s8v vals = {0, 0, 0, 0, 0, 0, 0, 0};
    if (rr < navail) {
      int eid = bucket[base + rr];
      const float* p = edge_attr + (size_t)eid * ED + cc;
      const float4 v0 = *(const float4*)(p);
      const float4 v1 = *(const float4*)(p + 4);
      vals[0] = f2bf(v0.x); vals[1] = f2bf(v0.y); vals[2] = f2bf(v0.z); vals[3] = f2bf(v0.w);
      vals[4] = f2bf(v1.x); vals[5] = f2bf(v1.y); vals[6] = f2bf(v1.z); vals[7] = f2bf(v1.w);
    }
    int byte = (rr * 256 + cc * 2) ^ ((rr & 7) << 4);
    *(s8v*)((char*)smem + byte) = vals;
  }
  __syncthreads();

  // ---- GEMM1 (swapped), K=128: wave w -> H1 cols [32w, 32w+32) ----
  f4v acc1[2][8];
  #pragma unroll
  for (int n = 0; n < 2; ++n)
    #pragma unroll
    for (int m = 0; m < 8; ++m)
      acc1[n][m] = (f4v){0.f, 0.f, 0.f, 0.f};

  for (int ks = 0; ks < 4; ++ks) {
    s8v wf0 = *(const s8v*)(w1ep + (((ks * 512 + 32 * w + ll) * 4 + lh) << 3));
    s8v wf1 = *(const s8v*)(w1ep + (((ks * 512 + 32 * w + 16 + ll) * 4 + lh) << 3));
    #pragma unroll
    for (int m = 0; m < 8; ++m) {
      int row = 16 * m + ll;
      int byte = (row * 256 + ks * 64 + lh * 16) ^ ((row & 7) << 4);
      s8v hf = *(const s8v*)((const char*)smem + byte);
      acc1[0][m] = __builtin_amdgcn_mfma_f32_16x16x32_bf16(wf0, hf, acc1[0][m], 0, 0, 0);
      acc1[1][m] = __builtin_amdgcn_mfma_f32_16x16x32_bf16(wf1, hf, acc1[1][m], 0, 0, 0);
    }
  }

  // ---- H1 = relu(acc1 + hx[erow[eid]] + b1) -> LDS [128][512] swizzled ----
  // hx loads here only, consumed immediately (no spill). erow/bucket 4B
  // reads are L2-hot; hx rows confined to this bucket's 128KB slab.
  {
    int rids[8];
    #pragma unroll
    for (int m = 0; m < 8; ++m) {
      int row = 16 * m + ll;
      rids[m] = (row < navail) ? erow[bucket[base + row]] : 0;
    }
    #pragma unroll
    for (int n = 0; n < 2; ++n) {
      int lcb = 32 * w + 16 * n + 4 * lh;
      const float4 bv = *(const float4*)(b1 + lcb);
      #pragma unroll
      for (int m = 0; m < 8; ++m) {
        int row = 16 * m + ll;
        s4v hxg = *(const s4v*)(hx + (size_t)rids[m] * 512 + lcb);
        float v0 = acc1[n][m][0] + bv.x + bf2f((uint32_t)(uint16_t)hxg[0]);
        float v1 = acc1[n][m][1] + bv.y + bf2f((uint32_t)(uint16_t)hxg[1]);
        float v2 = acc1[n][m][2] + bv.z + bf2f((uint32_t)(uint16_t)hxg[2]);
        float v3 = acc1[n][m][3] + bv.w + bf2f((uint32_t)(uint16_t)hxg[3]);
        s4v o;
        o[0] = f2bf(v0 > 0.f ? v0 : 0.f);
        o[1] = f2bf(v1 > 0.f ? v1 : 0.f);
        o[2] = f2bf(v2 > 0.f ? v2 : 0.f);
        o[3] = f2bf(v3 > 0.f ? v3 : 0.f);
        int byte = (row * 1024 + lcb * 2) ^ ((row & 7) << 4);
        *(s4v*)(h1b + byte) = o;
      }
    }
  }
  __syncthreads();   // H1 visible; ea-tile reads done

  // ---- GEMM2 (swapped), full K=512: c2-tile (w&7), edge-half (w>>3) ----
  f4v acc2[4];
  #pragma unroll
  for (int m = 0; m < 4; ++m)
    acc2[m] = (f4v){0.f, 0.f, 0.f, 0.f};

  const int c2b = (w & 7) * 16;
  const int ehb = (w >> 3) * 64;
  for (int ks = 0; ks < 16; ++ks) {
    s8v wf = *(const s8v*)(w2p + (((ks * 128 + c2b + ll) * 4 + lh) << 3));
    #pragma unroll
    for (int m = 0; m < 4; ++m) {
      int row = ehb + 16 * m + ll;
      int byte = (row * 1024 + ks * 64 + lh * 16) ^ ((row & 7) << 4);
      s8v hf = *(const s8v*)(h1b + byte);
      acc2[m] = __builtin_amdgcn_mfma_f32_16x16x32_bf16(wf, hf, acc2[m], 0, 0, 0);
    }
  }
  __syncthreads();   // H1 reads done; ea-tile region reusable for out tile

  // ---- stage output tile [128][128] bf16 (swizzled) ----
  {
    int cb = c2b + 4 * lh;
    const float4 bv = *(const float4*)(b2 + cb);
    #pragma unroll
    for (int m = 0; m < 4; ++m) {
      int row = ehb + 16 * m + ll;
      s4v o;
      o[0] = f2bf(acc2[m][0] + bv.x);
      o[1] = f2bf(acc2[m][1] + bv.y);
      o[2] = f2bf(acc2[m][2] + bv.z);
      o[3] = f2bf(acc2[m][3] + bv.w);
      int byte = (row * 256 + cb * 2) ^ ((row & 7) << 4);
      *(s4v*)((char*)smem + byte) = o;
    }
  }
  __syncthreads();

  // ---- store: full 256B rows to ebuf[eid] (16 threads/row contiguous) ----
  {
    #pragma unroll
    for (int it = 0; it < 2; ++it) {
      int B = (tid + it * 1024) * 16;   // byte offset in [0,32768)
      int row = B >> 8;
      if (row < navail) {
        int eid = bucket[base + row];
        int lb = B ^ ((row & 7) << 4);
        s8v v = *(const s8v*)((const char*)smem + lb);
        *(s8v*)((char*)ebuf + (size_t)eid * 256 + (B & 255)) = v;
      }
    }
  }
}

// =======================================================================
// Edge kernel (FALLBACK = R10-benched full-GEMM1 version).
// =======================================================================
__launch_bounds__(1024, 4)
__global__ void edge_kernel(const short* __restrict__ xbf,
                            const float* __restrict__ edge_attr,
                            const short* __restrict__ w1p,
                            const float* __restrict__ b1,
                            const short* __restrict__ w2p,
                            const float* __restrict__ b2,
                            const int* __restrict__ erow,
                            unsigned short* __restrict__ ebuf) {
  __shared__ __align__(16) short smem[128 * 384 + 128 * 256];
  char* const h1b = (char*)smem + 128 * 384 * 2;
  int* const rid = (int*)h1b;
  const int tid = threadIdx.x;
  const int lane = tid & 63;
  const int w = tid >> 6;
  const int lh = lane >> 4;
  const int ll = lane & 15;
  const int e0 = blockIdx.x * 128;

  if (tid < 128) {
    int e = e0 + tid;
    rid[tid] = (e < NE) ? erow[e] : 0;
  }
  __syncthreads();

  #pragma unroll
  for (int it = 0; it < 6; ++it) {
    int ch = tid + it * 1024;
    int rr = ch / 48;
    int cc = (ch - rr * 48) * 8;
    s8v vals = {0, 0, 0, 0, 0, 0, 0, 0};
    if (e0 + rr < NE) {
      if (cc < ND) {
        vals = *(const s8v*)(xbf + (size_t)rid[rr] * ND + cc);
      } else {
        const float* p = edge_attr + (size_t)(e0 + rr) * ED + (cc - ND);
        const float4 v0 = *(const float4*)(p);
        const float4 v1 = *(const float4*)(p + 4);
        vals[0] = f2bf(v0.x); vals[1] = f2bf(v0.y); vals[2] = f2bf(v0.z); vals[3] = f2bf(v0.w);
        vals[4] = f2bf(v1.x); vals[5] = f2bf(v1.y); vals[6] = f2bf(v1.z); vals[7] = f2bf(v1.w);
      }
    }
    int byte = (rr * 768 + cc * 2) ^ ((rr & 7) << 4);
    *(s8v*)((char*)smem + byte) = vals;
  }
  __syncthreads();

  f4v acc1[2][8];
  #pragma unroll
  for (int n = 0; n < 2; ++n)
    #pragma unroll
    for (int m = 0; m < 8; ++m)
      acc1[n][m] = (f4v){0.f, 0.f, 0.f, 0.f};

  for (int ks = 0; ks < 12; ++ks) {
    s8v wf0 = *(const s8v*)(w1p + (((ks * 512 + w * 16 + ll) * 4 + lh) << 3));
    s8v wf1 = *(const s8v*)(w1p + (((ks * 512 + 256 + w * 16 + ll) * 4 + lh) << 3));
    #pragma unroll
    for (int mh = 0; mh < 2; ++mh) {
      s8v hf[4];
      #pragma unroll
      for (int m = 0; m < 4; ++m) {
        int row = 64 * mh + 16 * m + ll;
        int byte = (row * 768 + ks * 64 + lh * 16) ^ ((row & 7) << 4);
        hf[m] = *(const s8v*)((const char*)smem + byte);
      }
      #pragma unroll
      for (int m = 0; m < 4; ++m) {
        acc1[0][4 * mh + m] = __builtin_amdgcn_mfma_f32_16x16x32_bf16(wf0, hf[m], acc1[0][4 * mh + m], 0, 0, 0);
        acc1[1][4 * mh + m] = __builtin_amdgcn_mfma_f32_16x16x32_bf16(wf1, hf[m], acc1[1][4 * mh + m], 0, 0, 0);
      }
    }
  }
  __syncthreads();

  f4v acc2[4];
  #pragma unroll
  for (int m = 0; m < 4; ++m)
    acc2[m] = (f4v){0.f, 0.f, 0.f, 0.f};

  #pragma unroll
  for (int half = 0; half < 2; ++half) {
    {
      int lcb = w * 16 + 4 * lh;
      const float4 bv = *(const float4*)(b1 + half * 256 + lcb);
      #pragma unroll
      for (int m = 0; m < 8; ++m) {
        int row = 16 * m + ll;
        s4v o;
        float v0 = acc1[half][m][0] + bv.x; o[0] = f2bf(v0 > 0.f ? v0 : 0.f);
        float v1 = acc1[half][m][1] + bv.y; o[1] = f2bf(v1 > 0.f ? v1 : 0.f);
        float v2 = acc1[half][m][2] + bv.z; o[2] = f2bf(v2 > 0.f ? v2 : 0.f);
        float v3 = acc1[half][m][3] + bv.w; o[3] = f2bf(v3 > 0.f ? v3 : 0.f);
        int byte = (row * 512 + lcb * 2) ^ ((row & 7) << 4);
        *(s4v*)(h1b + byte) = o;
      }
    }
    __syncthreads();

    for (int ksl = 0; ksl < 8; ++ksl) {
      int ksg = half * 8 + ksl;
      s8v wf = *(const s8v*)(w2p + (((ksg * 128 + (w & 7) * 16 + ll) * 4 + lh) << 3));
      #pragma unroll
      for (int m = 0; m < 4; ++m) {
        int row = 64 * (w >> 3) + 16 * m + ll;
        int byte = (row * 512 + ksl * 64 + lh * 16) ^ ((row & 7) << 4);
        s8v hf = *(const s8v*)(h1b + byte);
        acc2[m] = __builtin_amdgcn_mfma_f32_16x16x32_bf16(wf, hf, acc2[m], 0, 0, 0);
      }
    }
    __syncthreads();
  }

  {
    int cb = (w & 7) * 16 + 4 * lh;
    const float4 bv = *(const float4*)(b2 + cb);
    #pragma unroll
    for (int m = 0; m < 4; ++m) {
      int row = 64 * (w >> 3) + 16 * m + ll;
      s4v o;
      o[0] = f2bf(acc2[m][0] + bv.x);
      o[1] = f2bf(acc2[m][1] + bv.y);
      o[2] = f2bf(acc2[m][2] + bv.z);
      o[3] = f2bf(acc2[m][3] + bv.w);
      int byte = (row * 256 + cb * 2) ^ ((row & 7) << 4);
      *(s4v*)((char*)smem + byte) = o;
    }
  }
  __syncthreads();

  {
    size_t g0 = (size_t)e0 * ED;
    #pragma unroll
    for (int it = 0; it < 2; ++it) {
      int B = (tid + it * 1024) * 16;
      int row = B >> 8;
      int lb = B ^ ((row & 7) << 4);
      s8v v = *(const s8v*)((const char*)smem + lb);
      if (e0 + row < NE)
        *(s8v*)((char*)(ebuf + g0) + B) = v;
    }
  }
}

// =======================================================================
// Node kernel: unchanged (R10/R11-benched, 16 waves).
// =======================================================================
__launch_bounds__(1024, 4)
__global__ void node_kernel(const float* __restrict__ x,
                            const short* __restrict__ xbf,
                            const float* __restrict__ u,
                            const short* __restrict__ w3p,
                            const float* __restrict__ b3,
                            const short* __restrict__ w4p,
                            const float* __restrict__ b4,
                            const float* __restrict__ gamma,
                            const float* __restrict__ beta,
                            const int* __restrict__ batch,
                            const unsigned short* __restrict__ aggbf,
                            float* __restrict__ out) {
  __shared__ __align__(16) short smem[64 * 1024];
  const int tid = threadIdx.x;
  const int lane = tid & 63;
  const int w = tid >> 6;
  const int lh = lane >> 4;
  const int ll = lane & 15;
  const int n0 = blockIdx.x * 64;

  #pragma unroll
  for (int it = 0; it < 4; ++it) {
    int ch = tid + it * 1024;
    if (ch < 3584) {
      int rr = ch / 56;
      int cc = (ch - rr * 56) * 8;
      s8v vals = {0, 0, 0, 0, 0, 0, 0, 0};
      int node = n0 + rr;
      if (node < NN) {
        if (cc < 256) {
          vals = *(const s8v*)(xbf + (size_t)node * ND + cc);
        } else if (cc < 384) {
          vals = *(const s8v*)(aggbf + (size_t)node * ED + (cc - 256));
        } else {
          const float* up = u + (size_t)batch[node] * GD + (cc - 384);
          const float4 v0 = *(const float4*)(up);
          const float4 v1 = *(const float4*)(up + 4);
          vals[0] = f2bf(v0.x); vals[1] = f2bf(v0.y); vals[2] = f2bf(v0.z); vals[3] = f2bf(v0.w);
          vals[4] = f2bf(v1.x); vals[5] = f2bf(v1.y); vals[6] = f2bf(v1.z); vals[7] = f2bf(v1.w);
        }
      }
      int byte = (rr * 896 + cc * 2) ^ ((rr & 7) << 4);
      *(s8v*)((char*)smem + byte) = vals;
    }
  }
  __syncthreads();

  f4v acc3[4][4];
  #pragma unroll
  for (int n = 0; n < 4; ++n)
    #pragma unroll
    for (int m = 0; m < 4; ++m)
      acc3[n][m] = (f4v){0.f, 0.f, 0.f, 0.f};

  for (int ks = 0; ks < 14; ++ks) {
    s8v af[4];
    #pragma unroll
    for (int m = 0; m < 4; ++m) {
      int row = 16 * m + ll;
      int byte = (row * 896 + ks * 64 + lh * 16) ^ ((row & 7) << 4);
      af[m] = *(const s8v*)((const char*)smem + byte);
    }
    #pragma unroll
    for (int n = 0; n < 4; ++n) {
      s8v wf = *(const s8v*)(w3p + (((ks * 1024 + w * 64 + 16 * n + ll) * 4 + lh) << 3));
      #pragma unroll
      for (int m = 0; m < 4; ++m)
        acc3[n][m] = __builtin_amdgcn_mfma_f32_16x16x32_bf16(wf, af[m], acc3[n][m], 0, 0, 0);
    }
  }
  __syncthreads();

  #pragma unroll
  for (int n = 0; n < 4; ++n) {
    int cb = w * 64 + 16 * n + 4 * lh;
    const float4 bv = *(const float4*)(b3 + cb);
    #pragma unroll
    for (int m = 0; m < 4; ++m) {
      int row = 16 * m + ll;
      s4v o;
      float v0 = acc3[n][m][0] + bv.x; o[0] = f2bf(v0 > 0.f ? v0 : 0.f);
      float v1 = acc3[n][m][1] + bv.y; o[1] = f2bf(v1 > 0.f ? v1 : 0.f);
      float v2 = acc3[n][m][2] + bv.z; o[2] = f2bf(v2 > 0.f ? v2 : 0.f);
      float v3 = acc3[n][m][3] + bv.w; o[3] = f2bf(v3 > 0.f ? v3 : 0.f);
      int byte = (row * 2048 + cb * 2) ^ ((row & 7) << 4);
      *(s4v*)((char*)smem + byte) = o;
    }
  }
  __syncthreads();

  f4v acc4[4];
  #pragma unroll
  for (int m = 0; m < 4; ++m)
    acc4[m] = (f4v){0.f, 0.f, 0.f, 0.f};

  for (int ks = 0; ks < 32; ++ks) {
    s8v wf = *(const s8v*)(w4p + (((ks * 256 + w * 16 + ll) * 4 + lh) << 3));
    #pragma unroll
    for (int m = 0; m < 4; ++m) {
      int row = 16 * m + ll;
      int byte = (row * 2048 + ks * 64 + lh * 16) ^ ((row & 7) << 4);
      s8v hf = *(const s8v*)((const char*)smem + byte);
      acc4[m] = __builtin_amdgcn_mfma_f32_16x16x32_bf16(wf, hf, acc4[m], 0, 0, 0);
    }
  }
  __syncthreads();

  float* yb = (float*)smem;
  {
    int cb = w * 16 + 4 * lh;
    const float4 bv = *(const float4*)(b4 + cb);
    #pragma unroll
    for (int m = 0; m < 4; ++m) {
      int row = 16 * m + ll;
      int node = n0 + row;
      float4 xv = {0.f, 0.f, 0.f, 0.f};
      if (node < NN) xv = *(const float4*)(x + (size_t)node * ND + cb);
      f4v o;
      o[0] = acc4[m][0] + bv.x + xv.x;
      o[1] = acc4[m][1] + bv.y + xv.y;
      o[2] = acc4[m][2] + bv.z + xv.z;
      o[3] = acc4[m][3] + bv.w + xv.w;
      *(f4v*)(yb + row * 260 + cb) = o;
    }
  }
  __syncthreads();

  {
    int row = tid >> 4, sub = tid & 15;
    int node = n0 + row;
    float v[16];
    float sum = 0.f, ssq = 0.f;
    #pragma unroll
    for (int i = 0; i < 4; ++i) {
      const float4 t = *(const float4*)(yb + row * 260 + (i * 16 + sub) * 4);
      v[i * 4 + 0] = t.x; v[i * 4 + 1] = t.y; v[i * 4 + 2] = t.z; v[i * 4 + 3] = t.w;
      sum += t.x + t.y + t.z + t.w;
      ssq += t.x * t.x + t.y * t.y + t.z * t.z + t.w * t.w;
    }
    #pragma unroll
    for (int d = 1; d < 16; d <<= 1) {
      sum += __shfl_xor(sum, d);
      ssq += __shfl_xor(ssq, d);
    }
    float mu = sum * (1.f / 256.f);
    float var = ssq * (1.f / 256.f) - mu * mu;
    float rstd = rsqrtf(var + 1e-5f);
    if (node < NN) {
      #pragma unroll
      for (int i = 0; i < 4; ++i) {
        int c = (i * 16 + sub) * 4;
        const float4 g = *(const float4*)(gamma + c);
        const float4 be = *(const float4*)(beta + c);
        float4 o;
        o.x = (v[i * 4 + 0] - mu) * rstd * g.x + be.x;
        o.y = (v[i * 4 + 1] - mu) * rstd * g.y + be.y;
        o.z = (v[i * 4 + 2] - mu) * rstd * g.z + be.z;
        o.w = (v[i * 4 + 3] - mu) * rstd * g.w + be.w;
        *(float4*)(out + (size_t)node * ND + c) = o;
      }
    }
  }
}

extern "C" void kernel_launch(void* const* d_in, const int* in_sizes, int n_in,
                              void* d_out, int out_size, void* d_ws, size_t ws_size,
                              hipStream_t stream) {
  const float* x    = (const float*)d_in[0];
  const float* ea   = (const float*)d_in[1];
  const float* u    = (const float*)d_in[2];
  const float* W1   = (const float*)d_in[3];
  const float* b1   = (const float*)d_in[4];
  const float* W2   = (const float*)d_in[5];
  const float* b2   = (const float*)d_in[6];
  const float* W3   = (const float*)d_in[7];
  const float* b3   = (const float*)d_in[8];
  const float* W4   = (const float*)d_in[9];
  const float* b4   = (const float*)d_in[10];
  const float* gamma = (const float*)d_in[11];
  const float* beta  = (const float*)d_in[12];
  const int* eidx   = (const int*)d_in[13];
  const int* batch  = (const int*)d_in[14];
  float* out = (float*)d_out;

  char* p = (char*)d_ws;
  size_t off = 0;
  auto take = [&](size_t n) { char* r = p + off; off = (off + n + 255) & ~(size_t)255; return r; };
  short* xbf = (short*)take((size_t)NN * ND * 2);
  short* w1p = (short*)take((size_t)384 * 512 * 2);   // fallback full-K pack
  short* w2p = (short*)take((size_t)512 * 128 * 2);
  short* w3p = (short*)take((size_t)448 * 1024 * 2);
  short* w4p = (short*)take((size_t)1024 * 256 * 2);
  // contiguous counter region: cnt | bcnt (single memset)
  size_t cnt_off = off;
  unsigned int* cnt  = (unsigned int*)take((size_t)NN * 4);
  unsigned int* bcnt = (unsigned int*)take((size_t)NB * 4);
  size_t cnt_span = off - cnt_off;
  int* elist = (int*)take((size_t)NN * MAXDEG * 4);
  unsigned short* aggbf = (unsigned short*)take((size_t)NN * ED * 2);
  unsigned short* ebuf = (unsigned short*)take((size_t)NE * ED * 2);
  // hx + bucket extras
  short* hxb  = (short*)take((size_t)NN * 512 * 2);
  short* w1xp = (short*)take((size_t)256 * 512 * 2);
  short* w1ep = (short*)take((size_t)128 * 512 * 2);
  int* bucket = (int*)take((size_t)NB * BCAP * 4);
  size_t need_hx = off;
  bool hxpath = ws_size >= need_hx;

  const int* erow = eidx;
  const int* ecol = eidx + NE;

  cvt_bf16_kernel<<<(NN * ND / 4 + 255) / 256, 256, 0, stream>>>(x, xbf, NN * ND);
  hipMemsetAsync(p + cnt_off, 0, cnt_span, stream);

  if (hxpath) {
    pack_all_kernel<<<(S1 + S2 + S3 + S4 + S5 + 255) / 256, 256, 0, stream>>>(
        W1, W2, W3, W4, w1xp, w1ep, w2p, w3p, w4p);
    bucket_build_kernel<<<(NE + 255) / 256, 256, 0, stream>>>(erow, ecol, bcnt, bucket, cnt, elist);
    hx_kernel<<<(NN + 63) / 64, 512, 0, stream>>>(xbf, w1xp, hxb);
    edge_hx_kernel<<<NB * 16, 1024, 0, stream>>>(hxb, ea, w1ep, b1, w2p, b2,
                                                 erow, bucket, bcnt, ebuf);
  } else {
    pack_w_kernel<<<(384 * 512 + 255) / 256, 256, 0, stream>>>(W1, w1p, 384, 512);
    pack_w_kernel<<<(512 * 128 + 255) / 256, 256, 0, stream>>>(W2, w2p, 512, 128);
    pack_w_kernel<<<(448 * 1024 + 255) / 256, 256, 0, stream>>>(W3, w3p, 448, 1024);
    pack_w_kernel<<<(1024 * 256 + 255) / 256, 256, 0, stream>>>(W4, w4p, 1024, 256);
    build_kernel<<<(NE + 255) / 256, 256, 0, stream>>>(ecol, cnt, elist);
    edge_kernel<<<(NE + 127) / 128, 1024, 0, stream>>>(xbf, ea, w1p, b1, w2p, b2, erow, ebuf);
  }
  agg_kernel<<<(NN + 3) / 4, 256, 0, stream>>>(ebuf, elist, cnt, aggbf);
  node_kernel<<<(NN + 63) / 64, 1024, 0, stream>>>(x, xbf, u, w3p, b3, w4p, b4,
                                                   gamma, beta, batch, aggbf, out);
}

// Round 13
// 729.528 us; speedup vs baseline: 1.2899x; 1.2899x over previous
//
#include <hip/hip_runtime.h>
#include <stdint.h>

#define NE 500000
#define NN 50000
#define ND 256
#define ED 128
#define GD 64
#define MAXDEG 64

typedef float f4v __attribute__((ext_vector_type(4)));
typedef short s8v __attribute__((ext_vector_type(8)));
typedef short s4v __attribute__((ext_vector_type(4)));

static __device__ __forceinline__ short f2bf(float f) {
  union { float f; uint32_t u; } v; v.f = f;
  uint32_t r = v.u + 0x7FFFu + ((v.u >> 16) & 1u);
  return (short)(r >> 16);
}
static __device__ __forceinline__ float bf2f(uint32_t u) {
  union { uint32_t u; float f; } v; v.u = u << 16; return v.f;
}

// ---- pack W[K][C] fp32 -> bf16 MFMA fragment order [ks][c][kh][j] ----
static __device__ __forceinline__ void pack_one(const float* __restrict__ src,
                                                short* __restrict__ dst, int C, int idx) {
  int k = idx / C, c = idx - k * C;
  int ks = k >> 5, kh = (k >> 3) & 3, j = k & 7;
  dst[(((ks * C + c) * 4 + kh) << 3) + j] = f2bf(src[idx]);
}

// =======================================================================
// Fused prep: x->bf16 cvt | pack W1..W4 | build per-dest elist.
// One launch saturates the chip instead of 6 serial small kernels.
// =======================================================================
#define J0 3200000   // cvt: NN*ND/4 threads, 4 elems each
#define J1 196608    // w1p 384x512
#define J2 65536     // w2p 512x128
#define J3 458752    // w3p 448x1024
#define J4 262144    // w4p 1024x256
#define J5 500000    // build elist
__global__ void prep_kernel(const float* __restrict__ x, short* __restrict__ xbf,
                            const float* __restrict__ W1, const float* __restrict__ W2,
                            const float* __restrict__ W3, const float* __restrict__ W4,
                            short* __restrict__ w1p, short* __restrict__ w2p,
                            short* __restrict__ w3p, short* __restrict__ w4p,
                            const int* __restrict__ ecol, unsigned int* __restrict__ cnt,
                            int* __restrict__ elist) {
  int idx = blockIdx.x * blockDim.x + threadIdx.x;
  if (idx < J0) {
    int i = idx * 4;
    const float4 v = *(const float4*)(x + i);
    s4v o; o[0] = f2bf(v.x); o[1] = f2bf(v.y); o[2] = f2bf(v.z); o[3] = f2bf(v.w);
    *(s4v*)(xbf + i) = o;
    return;
  }
  idx -= J0;
  if (idx < J1) { pack_one(W1, w1p, 512, idx); return; }
  idx -= J1;
  if (idx < J2) { pack_one(W2, w2p, 128, idx); return; }
  idx -= J2;
  if (idx < J3) { pack_one(W3, w3p, 1024, idx); return; }
  idx -= J3;
  if (idx < J4) { pack_one(W4, w4p, 256, idx); return; }
  idx -= J4;
  if (idx < J5) {
    int c = ecol[idx];
    unsigned int slot = atomicAdd(&cnt[c], 1u);
    if (slot < MAXDEG) elist[c * MAXDEG + slot] = idx;
  }
}

// ---- gather-mean: one wave per node, lane handles 2 dims ----
__global__ void agg_kernel(const unsigned short* __restrict__ ebuf,
                           const int* __restrict__ elist,
                           const unsigned int* __restrict__ cnt,
                           unsigned short* __restrict__ aggbf) {
  int tid = threadIdx.x;
  int lane = tid & 63;
  int node = blockIdx.x * 4 + (tid >> 6);
  if (node >= NN) return;
  unsigned int deg = cnt[node];
  unsigned int jend = deg < MAXDEG ? deg : MAXDEG;
  float a0 = 0.f, a1 = 0.f;
  const int* el = elist + (size_t)node * MAXDEG;
  for (unsigned int j = 0; j < jend; ++j) {
    int eid = el[j];
    uint32_t v = *(const uint32_t*)(ebuf + (size_t)eid * ED + 2 * lane);
    a0 += bf2f(v & 0xFFFFu);
    a1 += bf2f(v >> 16);
  }
  float rc = 1.0f / (deg > 0 ? (float)deg : 1.0f);
  uint32_t o = (uint32_t)(uint16_t)f2bf(a0 * rc) | ((uint32_t)(uint16_t)f2bf(a1 * rc) << 16);
  *(uint32_t*)(aggbf + (size_t)node * ED + 2 * lane) = o;
}

// =======================================================================
// Edge kernel: EXACT R8/R10-benched version (455us, WRITE=125MB, no spill).
// M=128 edges/WG, 16 waves. A1 [128][384] 96KB + H1-half [128][256] 64KB
// = 160KB. GEMM1: wave w -> col-tile w (half0) + 16+w (half1); GEMM2 as
// two K=256 passes. Coalesced full-line output store.
// NOTE: do NOT hold global loads in registers across GEMM phases — 64 AGPR
// acc + held loads > 128-reg budget at 4 waves/SIMD spills to scratch
// (R9: +560MB WRITE). hx-gather variants (R11/R12) lose more in prep +
// gather transactions than GEMM1's K-reduction saves.
// =======================================================================
__launch_bounds__(1024, 4)
__global__ void edge_kernel(const short* __restrict__ xbf,
                            const float* __restrict__ edge_attr,
                            const short* __restrict__ w1p,
                            const float* __restrict__ b1,
                            const short* __restrict__ w2p,
                            const float* __restrict__ b2,
                            const int* __restrict__ erow,
                            unsigned short* __restrict__ ebuf) {
  __shared__ __align__(16) short smem[128 * 384 + 128 * 256];  // 96KB + 64KB
  char* const h1b = (char*)smem + 128 * 384 * 2;               // H1 half region
  int* const rid = (int*)h1b;                                  // transient: dead before H1 writes
  const int tid = threadIdx.x;
  const int lane = tid & 63;
  const int w = tid >> 6;          // wave 0..15
  const int lh = lane >> 4;        // 0..3
  const int ll = lane & 15;        // 0..15
  const int e0 = blockIdx.x * 128;

  if (tid < 128) {
    int e = e0 + tid;
    rid[tid] = (e < NE) ? erow[e] : 0;
  }
  __syncthreads();

  // ---- stage A1 [128][384] bf16, XOR-swizzled rows (6 iters) ----
  #pragma unroll
  for (int it = 0; it < 6; ++it) {
    int ch = tid + it * 1024;            // 6144 chunks of 8 elems
    int rr = ch / 48;
    int cc = (ch - rr * 48) * 8;
    s8v vals = {0, 0, 0, 0, 0, 0, 0, 0};
    if (e0 + rr < NE) {
      if (cc < ND) {
        vals = *(const s8v*)(xbf + (size_t)rid[rr] * ND + cc);
      } else {
        const float* p = edge_attr + (size_t)(e0 + rr) * ED + (cc - ND);
        const float4 v0 = *(const float4*)(p);
        const float4 v1 = *(const float4*)(p + 4);
        vals[0] = f2bf(v0.x); vals[1] = f2bf(v0.y); vals[2] = f2bf(v0.z); vals[3] = f2bf(v0.w);
        vals[4] = f2bf(v1.x); vals[5] = f2bf(v1.y); vals[6] = f2bf(v1.z); vals[7] = f2bf(v1.w);
      }
    }
    int byte = (rr * 768 + cc * 2) ^ ((rr & 7) << 4);
    *(s8v*)((char*)smem + byte) = vals;
  }
  __syncthreads();

  // ---- GEMM1 (swapped): acc1[n][mt]; n=0 -> col-tile w (cols 16w),
  //      n=1 -> col-tile 16+w (cols 256+16w); mt = edge-tile 0..7 ----
  f4v acc1[2][8];
  #pragma unroll
  for (int n = 0; n < 2; ++n)
    #pragma unroll
    for (int m = 0; m < 8; ++m)
      acc1[n][m] = (f4v){0.f, 0.f, 0.f, 0.f};

  for (int ks = 0; ks < 12; ++ks) {
    s8v wf0 = *(const s8v*)(w1p + (((ks * 512 + w * 16 + ll) * 4 + lh) << 3));
    s8v wf1 = *(const s8v*)(w1p + (((ks * 512 + 256 + w * 16 + ll) * 4 + lh) << 3));
    #pragma unroll
    for (int mh = 0; mh < 2; ++mh) {
      s8v hf[4];
      #pragma unroll
      for (int m = 0; m < 4; ++m) {
        int row = 64 * mh + 16 * m + ll;
        int byte = (row * 768 + ks * 64 + lh * 16) ^ ((row & 7) << 4);
        hf[m] = *(const s8v*)((const char*)smem + byte);
      }
      #pragma unroll
      for (int m = 0; m < 4; ++m) {
        acc1[0][4 * mh + m] = __builtin_amdgcn_mfma_f32_16x16x32_bf16(wf0, hf[m], acc1[0][4 * mh + m], 0, 0, 0);
        acc1[1][4 * mh + m] = __builtin_amdgcn_mfma_f32_16x16x32_bf16(wf1, hf[m], acc1[1][4 * mh + m], 0, 0, 0);
      }
    }
  }
  __syncthreads();   // A1 reads done for GEMM1; rid dead from here

  // ---- GEMM2 accumulators: c2-tile (w&7), edge-quarter (w>>3) ----
  f4v acc2[4];
  #pragma unroll
  for (int m = 0; m < 4; ++m)
    acc2[m] = (f4v){0.f, 0.f, 0.f, 0.f};

  // ---- two half passes over H1 cols: write half -> GEMM2 K=256 ----
  #pragma unroll
  for (int half = 0; half < 2; ++half) {
    // write H1 half: wave w writes its col-tile (local cols 16w+4lh..+3)
    {
      int lcb = w * 16 + 4 * lh;                    // local col in [0,256)
      const float4 bv = *(const float4*)(b1 + half * 256 + lcb);
      #pragma unroll
      for (int m = 0; m < 8; ++m) {
        int row = 16 * m + ll;
        s4v o;
        float v0 = acc1[half][m][0] + bv.x; o[0] = f2bf(v0 > 0.f ? v0 : 0.f);
        float v1 = acc1[half][m][1] + bv.y; o[1] = f2bf(v1 > 0.f ? v1 : 0.f);
        float v2 = acc1[half][m][2] + bv.z; o[2] = f2bf(v2 > 0.f ? v2 : 0.f);
        float v3 = acc1[half][m][3] + bv.w; o[3] = f2bf(v3 > 0.f ? v3 : 0.f);
        int byte = (row * 512 + lcb * 2) ^ ((row & 7) << 4);
        *(s4v*)(h1b + byte) = o;
      }
    }
    __syncthreads();   // H1 half visible

    // GEMM2 partial: K = 256 (8 ks)
    for (int ksl = 0; ksl < 8; ++ksl) {
      int ksg = half * 8 + ksl;
      s8v wf = *(const s8v*)(w2p + (((ksg * 128 + (w & 7) * 16 + ll) * 4 + lh) << 3));
      #pragma unroll
      for (int m = 0; m < 4; ++m) {
        int row = 64 * (w >> 3) + 16 * m + ll;
        int byte = (row * 512 + ksl * 64 + lh * 16) ^ ((row & 7) << 4);
        s8v hf = *(const s8v*)(h1b + byte);
        acc2[m] = __builtin_amdgcn_mfma_f32_16x16x32_bf16(wf, hf, acc2[m], 0, 0, 0);
      }
    }
    __syncthreads();   // all GEMM2 reads of this half done before overwrite
  }

  // ---- stage output tile [128][128] bf16 in A1 region (swizzled) ----
  {
    int cb = (w & 7) * 16 + 4 * lh;
    const float4 bv = *(const float4*)(b2 + cb);
    #pragma unroll
    for (int m = 0; m < 4; ++m) {
      int row = 64 * (w >> 3) + 16 * m + ll;
      s4v o;
      o[0] = f2bf(acc2[m][0] + bv.x);
      o[1] = f2bf(acc2[m][1] + bv.y);
      o[2] = f2bf(acc2[m][2] + bv.z);
      o[3] = f2bf(acc2[m][3] + bv.w);
      int byte = (row * 256 + cb * 2) ^ ((row & 7) << 4);
      *(s4v*)((char*)smem + byte) = o;
    }
  }
  __syncthreads();

  // ---- coalesced store: 1024 threads x 2 x 16B = full 32KB tile ----
  {
    size_t g0 = (size_t)e0 * ED;        // elements
    #pragma unroll
    for (int it = 0; it < 2; ++it) {
      int B = (tid + it * 1024) * 16;   // byte offset in [0,32768)
      int row = B >> 8;
      int lb = B ^ ((row & 7) << 4);
      s8v v = *(const s8v*)((const char*)smem + lb);
      if (e0 + row < NE)
        *(s8v*)((char*)(ebuf + g0) + B) = v;
    }
  }
}

// =======================================================================
// Node kernel: R10-benched 16-wave version.
// =======================================================================
__launch_bounds__(1024, 4)
__global__ void node_kernel(const float* __restrict__ x,
                            const short* __restrict__ xbf,
                            const float* __restrict__ u,
                            const short* __restrict__ w3p,
                            const float* __restrict__ b3,
                            const short* __restrict__ w4p,
                            const float* __restrict__ b4,
                            const float* __restrict__ gamma,
                            const float* __restrict__ beta,
                            const int* __restrict__ batch,
                            const unsigned short* __restrict__ aggbf,
                            float* __restrict__ out) {
  __shared__ __align__(16) short smem[64 * 1024];
  const int tid = threadIdx.x;
  const int lane = tid & 63;
  const int w = tid >> 6;
  const int lh = lane >> 4;
  const int ll = lane & 15;
  const int n0 = blockIdx.x * 64;

  #pragma unroll
  for (int it = 0; it < 4; ++it) {
    int ch = tid + it * 1024;
    if (ch < 3584) {
      int rr = ch / 56;
      int cc = (ch - rr * 56) * 8;
      s8v vals = {0, 0, 0, 0, 0, 0, 0, 0};
      int node = n0 + rr;
      if (node < NN) {
        if (cc < 256) {
          vals = *(const s8v*)(xbf + (size_t)node * ND + cc);
        } else if (cc < 384) {
          vals = *(const s8v*)(aggbf + (size_t)node * ED + (cc - 256));
        } else {
          const float* up = u + (size_t)batch[node] * GD + (cc - 384);
          const float4 v0 = *(const float4*)(up);
          const float4 v1 = *(const float4*)(up + 4);
          vals[0] = f2bf(v0.x); vals[1] = f2bf(v0.y); vals[2] = f2bf(v0.z); vals[3] = f2bf(v0.w);
          vals[4] = f2bf(v1.x); vals[5] = f2bf(v1.y); vals[6] = f2bf(v1.z); vals[7] = f2bf(v1.w);
        }
      }
      int byte = (rr * 896 + cc * 2) ^ ((rr & 7) << 4);
      *(s8v*)((char*)smem + byte) = vals;
    }
  }
  __syncthreads();

  f4v acc3[4][4];
  #pragma unroll
  for (int n = 0; n < 4; ++n)
    #pragma unroll
    for (int m = 0; m < 4; ++m)
      acc3[n][m] = (f4v){0.f, 0.f, 0.f, 0.f};

  for (int ks = 0; ks < 14; ++ks) {
    s8v af[4];
    #pragma unroll
    for (int m = 0; m < 4; ++m) {
      int row = 16 * m + ll;
      int byte = (row * 896 + ks * 64 + lh * 16) ^ ((row & 7) << 4);
      af[m] = *(const s8v*)((const char*)smem + byte);
    }
    #pragma unroll
    for (int n = 0; n < 4; ++n) {
      s8v wf = *(const s8v*)(w3p + (((ks * 1024 + w * 64 + 16 * n + ll) * 4 + lh) << 3));
      #pragma unroll
      for (int m = 0; m < 4; ++m)
        acc3[n][m] = __builtin_amdgcn_mfma_f32_16x16x32_bf16(wf, af[m], acc3[n][m], 0, 0, 0);
    }
  }
  __syncthreads();

  #pragma unroll
  for (int n = 0; n < 4; ++n) {
    int cb = w * 64 + 16 * n + 4 * lh;
    const float4 bv = *(const float4*)(b3 + cb);
    #pragma unroll
    for (int m = 0; m < 4; ++m) {
      int row = 16 * m + ll;
      s4v o;
      float v0 = acc3[n][m][0] + bv.x; o[0] = f2bf(v0 > 0.f ? v0 : 0.f);
      float v1 = acc3[n][m][1] + bv.y; o[1] = f2bf(v1 > 0.f ? v1 : 0.f);
      float v2 = acc3[n][m][2] + bv.z; o[2] = f2bf(v2 > 0.f ? v2 : 0.f);
      float v3 = acc3[n][m][3] + bv.w; o[3] = f2bf(v3 > 0.f ? v3 : 0.f);
      int byte = (row * 2048 + cb * 2) ^ ((row & 7) << 4);
      *(s4v*)((char*)smem + byte) = o;
    }
  }
  __syncthreads();

  f4v acc4[4];
  #pragma unroll
  for (int m = 0; m < 4; ++m)
    acc4[m] = (f4v){0.f, 0.f, 0.f, 0.f};

  for (int ks = 0; ks < 32; ++ks) {
    s8v wf = *(const s8v*)(w4p + (((ks * 256 + w * 16 + ll) * 4 + lh) << 3));
    #pragma unroll
    for (int m = 0; m < 4; ++m) {
      int row = 16 * m + ll;
      int byte = (row * 2048 + ks * 64 + lh * 16) ^ ((row & 7) << 4);
      s8v hf = *(const s8v*)((const char*)smem + byte);
      acc4[m] = __builtin_amdgcn_mfma_f32_16x16x32_bf16(wf, hf, acc4[m], 0, 0, 0);
    }
  }
  __syncthreads();

  float* yb = (float*)smem;
  {
    int cb = w * 16 + 4 * lh;
    const float4 bv = *(const float4*)(b4 + cb);
    #pragma unroll
    for (int m = 0; m < 4; ++m) {
      int row = 16 * m + ll;
      int node = n0 + row;
      float4 xv = {0.f, 0.f, 0.f, 0.f};
      if (node < NN) xv = *(const float4*)(x + (size_t)node * ND + cb);
      f4v o;
      o[0] = acc4[m][0] + bv.x + xv.x;
      o[1] = acc4[m][1] + bv.y + xv.y;
      o[2] = acc4[m][2] + bv.z + xv.z;
      o[3] = acc4[m][3] + bv.w + xv.w;
      *(f4v*)(yb + row * 260 + cb) = o;
    }
  }
  __syncthreads();

  {
    int row = tid >> 4, sub = tid & 15;
    int node = n0 + row;
    float v[16];
    float sum = 0.f, ssq = 0.f;
    #pragma unroll
    for (int i = 0; i < 4; ++i) {
      const float4 t = *(const float4*)(yb + row * 260 + (i * 16 + sub) * 4);
      v[i * 4 + 0] = t.x; v[i * 4 + 1] = t.y; v[i * 4 + 2] = t.z; v[i * 4 + 3] = t.w;
      sum += t.x + t.y + t.z + t.w;
      ssq += t.x * t.x + t.y * t.y + t.z * t.z + t.w * t.w;
    }
    #pragma unroll
    for (int d = 1; d < 16; d <<= 1) {
      sum += __shfl_xor(sum, d);
      ssq += __shfl_xor(ssq, d);
    }
    float mu = sum * (1.f / 256.f);
    float var = ssq * (1.f / 256.f) - mu * mu;
    float rstd = rsqrtf(var + 1e-5f);
    if (node < NN) {
      #pragma unroll
      for (int i = 0; i < 4; ++i) {
        int c = (i * 16 + sub) * 4;
        const float4 g = *(const float4*)(gamma + c);
        const float4 be = *(const float4*)(beta + c);
        float4 o;
        o.x = (v[i * 4 + 0] - mu) * rstd * g.x + be.x;
        o.y = (v[i * 4 + 1] - mu) * rstd * g.y + be.y;
        o.z = (v[i * 4 + 2] - mu) * rstd * g.z + be.z;
        o.w = (v[i * 4 + 3] - mu) * rstd * g.w + be.w;
        *(float4*)(out + (size_t)node * ND + c) = o;
      }
    }
  }
}

extern "C" void kernel_launch(void* const* d_in, const int* in_sizes, int n_in,
                              void* d_out, int out_size, void* d_ws, size_t ws_size,
                              hipStream_t stream) {
  const float* x    = (const float*)d_in[0];
  const float* ea   = (const float*)d_in[1];
  const float* u    = (const float*)d_in[2];
  const float* W1   = (const float*)d_in[3];
  const float* b1   = (const float*)d_in[4];
  const float* W2   = (const float*)d_in[5];
  const float* b2   = (const float*)d_in[6];
  const float* W3   = (const float*)d_in[7];
  const float* b3   = (const float*)d_in[8];
  const float* W4   = (const float*)d_in[9];
  const float* b4   = (const float*)d_in[10];
  const float* gamma = (const float*)d_in[11];
  const float* beta  = (const float*)d_in[12];
  const int* eidx   = (const int*)d_in[13];
  const int* batch  = (const int*)d_in[14];
  float* out = (float*)d_out;

  char* p = (char*)d_ws;
  size_t off = 0;
  auto take = [&](size_t n) { char* r = p + off; off = (off + n + 255) & ~(size_t)255; return r; };
  short* xbf = (short*)take((size_t)NN * ND * 2);
  short* w1p = (short*)take((size_t)384 * 512 * 2);
  short* w2p = (short*)take((size_t)512 * 128 * 2);
  short* w3p = (short*)take((size_t)448 * 1024 * 2);
  short* w4p = (short*)take((size_t)1024 * 256 * 2);
  unsigned int* cnt = (unsigned int*)take((size_t)NN * 4);
  int* elist = (int*)take((size_t)NN * MAXDEG * 4);
  unsigned short* aggbf = (unsigned short*)take((size_t)NN * ED * 2);
  unsigned short* ebuf = (unsigned short*)take((size_t)NE * ED * 2);

  const int* erow = eidx;
  const int* ecol = eidx + NE;

  hipMemsetAsync(cnt, 0, (size_t)NN * 4, stream);
  {
    const int total = J0 + J1 + J2 + J3 + J4 + J5;
    prep_kernel<<<(total + 255) / 256, 256, 0, stream>>>(x, xbf, W1, W2, W3, W4,
                                                         w1p, w2p, w3p, w4p,
                                                         ecol, cnt, elist);
  }
  edge_kernel<<<(NE + 127) / 128, 1024, 0, stream>>>(xbf, ea, w1p, b1, w2p, b2, erow, ebuf);
  agg_kernel<<<(NN + 3) / 4, 256, 0, stream>>>(ebuf, elist, cnt, aggbf);
  node_kernel<<<(NN + 63) / 64, 1024, 0, stream>>>(x, xbf, u, w3p, b3, w4p, b4,
                                                   gamma, beta, batch, aggbf, out);
}

// Round 14
// 696.085 us; speedup vs baseline: 1.3518x; 1.0480x over previous
//
#include <hip/hip_runtime.h>
#include <stdint.h>

#define NE 500000
#define NN 50000
#define ND 256
#define ED 128
#define GD 64
#define MAXDEG 64

typedef float f4v __attribute__((ext_vector_type(4)));
typedef short s8v __attribute__((ext_vector_type(8)));
typedef short s4v __attribute__((ext_vector_type(4)));

static __device__ __forceinline__ short f2bf(float f) {
  union { float f; uint32_t u; } v; v.f = f;
  uint32_t r = v.u + 0x7FFFu + ((v.u >> 16) & 1u);
  return (short)(r >> 16);
}
static __device__ __forceinline__ float bf2f(uint32_t u) {
  union { uint32_t u; float f; } v; v.u = u << 16; return v.f;
}

// ---- async global->LDS DMA, 16B per lane; LDS dest = wave-uniform base +
// lane*16 (HW-defined); global src is per-lane. ----
static __device__ __forceinline__ void gload_lds16(const void* g, void* l) {
  __builtin_amdgcn_global_load_lds(
      (const __attribute__((address_space(1))) unsigned int*)g,
      (__attribute__((address_space(3))) unsigned int*)l,
      16, 0, 0);
}

// ---- pack W[K][C] fp32 -> bf16 MFMA fragment order [ks][c][kh][j] ----
static __device__ __forceinline__ void pack_one(const float* __restrict__ src,
                                                short* __restrict__ dst, int C, int idx) {
  int k = idx / C, c = idx - k * C;
  int ks = k >> 5, kh = (k >> 3) & 3, j = k & 7;
  dst[(((ks * C + c) * 4 + kh) << 3) + j] = f2bf(src[idx]);
}

// =======================================================================
// Fused prep: x->bf16 cvt | pack W1..W4 | build per-dest elist.
// =======================================================================
#define J0 3200000   // cvt: NN*ND/4 threads, 4 elems each
#define J1 196608    // w1p 384x512
#define J2 65536     // w2p 512x128
#define J3 458752    // w3p 448x1024
#define J4 262144    // w4p 1024x256
#define J5 500000    // build elist
__global__ void prep_kernel(const float* __restrict__ x, short* __restrict__ xbf,
                            const float* __restrict__ W1, const float* __restrict__ W2,
                            const float* __restrict__ W3, const float* __restrict__ W4,
                            short* __restrict__ w1p, short* __restrict__ w2p,
                            short* __restrict__ w3p, short* __restrict__ w4p,
                            const int* __restrict__ ecol, unsigned int* __restrict__ cnt,
                            int* __restrict__ elist) {
  int idx = blockIdx.x * blockDim.x + threadIdx.x;
  if (idx < J0) {
    int i = idx * 4;
    const float4 v = *(const float4*)(x + i);
    s4v o; o[0] = f2bf(v.x); o[1] = f2bf(v.y); o[2] = f2bf(v.z); o[3] = f2bf(v.w);
    *(s4v*)(xbf + i) = o;
    return;
  }
  idx -= J0;
  if (idx < J1) { pack_one(W1, w1p, 512, idx); return; }
  idx -= J1;
  if (idx < J2) { pack_one(W2, w2p, 128, idx); return; }
  idx -= J2;
  if (idx < J3) { pack_one(W3, w3p, 1024, idx); return; }
  idx -= J3;
  if (idx < J4) { pack_one(W4, w4p, 256, idx); return; }
  idx -= J4;
  if (idx < J5) {
    int c = ecol[idx];
    unsigned int slot = atomicAdd(&cnt[c], 1u);
    if (slot < MAXDEG) elist[c * MAXDEG + slot] = idx;
  }
}

// ---- gather-mean: one wave per node, lane handles 2 dims ----
__global__ void agg_kernel(const unsigned short* __restrict__ ebuf,
                           const int* __restrict__ elist,
                           const unsigned int* __restrict__ cnt,
                           unsigned short* __restrict__ aggbf) {
  int tid = threadIdx.x;
  int lane = tid & 63;
  int node = blockIdx.x * 4 + (tid >> 6);
  if (node >= NN) return;
  unsigned int deg = cnt[node];
  unsigned int jend = deg < MAXDEG ? deg : MAXDEG;
  float a0 = 0.f, a1 = 0.f;
  const int* el = elist + (size_t)node * MAXDEG;
  for (unsigned int j = 0; j < jend; ++j) {
    int eid = el[j];
    uint32_t v = *(const uint32_t*)(ebuf + (size_t)eid * ED + 2 * lane);
    a0 += bf2f(v & 0xFFFFu);
    a1 += bf2f(v >> 16);
  }
  float rc = 1.0f / (deg > 0 ? (float)deg : 1.0f);
  uint32_t o = (uint32_t)(uint16_t)f2bf(a0 * rc) | ((uint32_t)(uint16_t)f2bf(a1 * rc) << 16);
  *(uint32_t*)(aggbf + (size_t)node * ED + 2 * lane) = o;
}

// =======================================================================
// Edge kernel: M=128 edges/WG, 16 waves. Same tiles/math as R13 (456us),
// restructured phases:
//  - A1 split: X [128][256]bf16 (64KB, xbf part) staged by global_load_lds
//    with SOURCE-swizzled octet (c ^ (row&7)); E [128][128]bf16 (32KB, ea
//    part) staged fp32->bf16 by VALU concurrently with the X DMA.
//  - rid LDS array dropped (per-lane erow reads).
//  - out-tile LDS staging dropped: direct 8B stores (R3-proven, no
//    competing stream -> no write amplification).
//  - barriers 8 -> 4.
// LDS: X 64KB + E 32KB + H1half 64KB = 160KB exactly.
// NOTE: no global loads held in registers across MFMA phases (R9: spill).
// =======================================================================
__launch_bounds__(1024, 4)
__global__ void edge_kernel(const short* __restrict__ xbf,
                            const float* __restrict__ edge_attr,
                            const short* __restrict__ w1p,
                            const float* __restrict__ b1,
                            const short* __restrict__ w2p,
                            const float* __restrict__ b2,
                            const int* __restrict__ erow,
                            unsigned short* __restrict__ ebuf) {
  __shared__ __align__(16) short smem[81920];       // 160KB
  char* const Xb = (char*)smem;                     // [128][256] bf16, 512B rows
  char* const Eb = (char*)smem + 65536;             // [128][128] bf16, 256B rows
  char* const Hb = (char*)smem + 98304;             // H1 half [128][256], XOR swz
  const int tid = threadIdx.x;
  const int lane = tid & 63;
  const int w = tid >> 6;          // wave 0..15
  const int lh = lane >> 4;        // 0..3
  const int ll = lane & 15;        // 0..15
  const int e0 = blockIdx.x * 128;

  // ---- X: DMA xbf rows (1KB = 2 rows per inst, 4 insts per wave) ----
  // LDS linear; swizzle folded into the per-lane GLOBAL octet index.
  {
    #pragma unroll
    for (int i = 0; i < 4; ++i) {
      int p = w * 4 + i;                     // row pair 0..63
      int row = 2 * p + (lane >> 5);
      // e0+row may exceed NE-1 on the tail block: erow read stays inside
      // the 1M-int eidx buffer (reads ecol values < NN) -> safe junk rows,
      // outputs guarded at the store.
      int rid = erow[e0 + row];
      int cg = (lane & 31) ^ (row & 7);      // source-swizzled octet
      gload_lds16(xbf + (size_t)rid * 256 + cg * 8, Xb + p * 1024);
    }
  }

  // ---- E: stage ea fp32 -> bf16, octet-swizzled (concurrent with DMA) ----
  #pragma unroll
  for (int it = 0; it < 2; ++it) {
    int id = tid + it * 1024;                // 2048 octets
    int row = id >> 4, oct = id & 15;
    s8v vals = {0, 0, 0, 0, 0, 0, 0, 0};
    if (e0 + row < NE) {
      const float* p = edge_attr + (size_t)(e0 + row) * ED + oct * 8;
      const float4 v0 = *(const float4*)(p);
      const float4 v1 = *(const float4*)(p + 4);
      vals[0] = f2bf(v0.x); vals[1] = f2bf(v0.y); vals[2] = f2bf(v0.z); vals[3] = f2bf(v0.w);
      vals[4] = f2bf(v1.x); vals[5] = f2bf(v1.y); vals[6] = f2bf(v1.z); vals[7] = f2bf(v1.w);
    }
    *(s8v*)(Eb + row * 256 + ((oct ^ (row & 7)) << 4)) = vals;
  }
  __syncthreads();   // drains vmcnt (DMA complete) + E writes visible

  // ---- GEMM1 (swapped): acc1[n][mt]; n=0 -> cols 16w, n=1 -> 256+16w ----
  f4v acc1[2][8];
  #pragma unroll
  for (int n = 0; n < 2; ++n)
    #pragma unroll
    for (int m = 0; m < 8; ++m)
      acc1[n][m] = (f4v){0.f, 0.f, 0.f, 0.f};

  // ks 0..7: k<256 from X
  for (int ks = 0; ks < 8; ++ks) {
    s8v wf0 = *(const s8v*)(w1p + (((ks * 512 + w * 16 + ll) * 4 + lh) << 3));
    s8v wf1 = *(const s8v*)(w1p + (((ks * 512 + 256 + w * 16 + ll) * 4 + lh) << 3));
    #pragma unroll
    for (int mh = 0; mh < 2; ++mh) {
      s8v hf[4];
      #pragma unroll
      for (int m = 0; m < 4; ++m) {
        int row = 64 * mh + 16 * m + ll;
        int byte = row * 512 + (((ks * 4 + lh) ^ (row & 7)) << 4);
        hf[m] = *(const s8v*)(Xb + byte);
      }
      #pragma unroll
      for (int m = 0; m < 4; ++m) {
        acc1[0][4 * mh + m] = __builtin_amdgcn_mfma_f32_16x16x32_bf16(wf0, hf[m], acc1[0][4 * mh + m], 0, 0, 0);
        acc1[1][4 * mh + m] = __builtin_amdgcn_mfma_f32_16x16x32_bf16(wf1, hf[m], acc1[1][4 * mh + m], 0, 0, 0);
      }
    }
  }
  // ks 8..11: k>=256 from E
  for (int ks = 8; ks < 12; ++ks) {
    s8v wf0 = *(const s8v*)(w1p + (((ks * 512 + w * 16 + ll) * 4 + lh) << 3));
    s8v wf1 = *(const s8v*)(w1p + (((ks * 512 + 256 + w * 16 + ll) * 4 + lh) << 3));
    #pragma unroll
    for (int mh = 0; mh < 2; ++mh) {
      s8v hf[4];
      #pragma unroll
      for (int m = 0; m < 4; ++m) {
        int row = 64 * mh + 16 * m + ll;
        int byte = row * 256 + ((((ks - 8) * 4 + lh) ^ (row & 7)) << 4);
        hf[m] = *(const s8v*)(Eb + byte);
      }
      #pragma unroll
      for (int m = 0; m < 4; ++m) {
        acc1[0][4 * mh + m] = __builtin_amdgcn_mfma_f32_16x16x32_bf16(wf0, hf[m], acc1[0][4 * mh + m], 0, 0, 0);
        acc1[1][4 * mh + m] = __builtin_amdgcn_mfma_f32_16x16x32_bf16(wf1, hf[m], acc1[1][4 * mh + m], 0, 0, 0);
      }
    }
  }

  // ---- GEMM2 accumulators: c2-tile (w&7), edge-quarter (w>>3) ----
  f4v acc2[4];
  #pragma unroll
  for (int m = 0; m < 4; ++m)
    acc2[m] = (f4v){0.f, 0.f, 0.f, 0.f};

  // ---- half 0: write H1 (no leading barrier needed: per-wave cols,
  //      region not aliased) -> barrier -> GEMM2 K=256 ----
  {
    int lcb = w * 16 + 4 * lh;
    const float4 bv = *(const float4*)(b1 + lcb);
    #pragma unroll
    for (int m = 0; m < 8; ++m) {
      int row = 16 * m + ll;
      s4v o;
      float v0 = acc1[0][m][0] + bv.x; o[0] = f2bf(v0 > 0.f ? v0 : 0.f);
      float v1 = acc1[0][m][1] + bv.y; o[1] = f2bf(v1 > 0.f ? v1 : 0.f);
      float v2 = acc1[0][m][2] + bv.z; o[2] = f2bf(v2 > 0.f ? v2 : 0.f);
      float v3 = acc1[0][m][3] + bv.w; o[3] = f2bf(v3 > 0.f ? v3 : 0.f);
      int byte = (row * 512 + lcb * 2) ^ ((row & 7) << 4);
      *(s4v*)(Hb + byte) = o;
    }
  }
  __syncthreads();

  for (int ksl = 0; ksl < 8; ++ksl) {
    s8v wf = *(const s8v*)(w2p + (((ksl * 128 + (w & 7) * 16 + ll) * 4 + lh) << 3));
    #pragma unroll
    for (int m = 0; m < 4; ++m) {
      int row = 64 * (w >> 3) + 16 * m + ll;
      int byte = (row * 512 + ksl * 64 + lh * 16) ^ ((row & 7) << 4);
      s8v hf = *(const s8v*)(Hb + byte);
      acc2[m] = __builtin_amdgcn_mfma_f32_16x16x32_bf16(wf, hf, acc2[m], 0, 0, 0);
    }
  }
  __syncthreads();   // half-0 reads done before overwrite

  // ---- half 1 ----
  {
    int lcb = w * 16 + 4 * lh;
    const float4 bv = *(const float4*)(b1 + 256 + lcb);
    #pragma unroll
    for (int m = 0; m < 8; ++m) {
      int row = 16 * m + ll;
      s4v o;
      float v0 = acc1[1][m][0] + bv.x; o[0] = f2bf(v0 > 0.f ? v0 : 0.f);
      float v1 = acc1[1][m][1] + bv.y; o[1] = f2bf(v1 > 0.f ? v1 : 0.f);
      float v2 = acc1[1][m][2] + bv.z; o[2] = f2bf(v2 > 0.f ? v2 : 0.f);
      float v3 = acc1[1][m][3] + bv.w; o[3] = f2bf(v3 > 0.f ? v3 : 0.f);
      int byte = (row * 512 + lcb * 2) ^ ((row & 7) << 4);
      *(s4v*)(Hb + byte) = o;
    }
  }
  __syncthreads();

  for (int ksl = 0; ksl < 8; ++ksl) {
    int ksg = 8 + ksl;
    s8v wf = *(const s8v*)(w2p + (((ksg * 128 + (w & 7) * 16 + ll) * 4 + lh) << 3));
    #pragma unroll
    for (int m = 0; m < 4; ++m) {
      int row = 64 * (w >> 3) + 16 * m + ll;
      int byte = (row * 512 + ksl * 64 + lh * 16) ^ ((row & 7) << 4);
      s8v hf = *(const s8v*)(Hb + byte);
      acc2[m] = __builtin_amdgcn_mfma_f32_16x16x32_bf16(wf, hf, acc2[m], 0, 0, 0);
    }
  }

  // ---- epilogue: direct 8B stores (16 rows x 32B segments per inst) ----
  {
    int cb = (w & 7) * 16 + 4 * lh;
    const float4 bv = *(const float4*)(b2 + cb);
    #pragma unroll
    for (int m = 0; m < 4; ++m) {
      int row = 64 * (w >> 3) + 16 * m + ll;
      int e = e0 + row;
      if (e < NE) {
        s4v o;
        o[0] = f2bf(acc2[m][0] + bv.x);
        o[1] = f2bf(acc2[m][1] + bv.y);
        o[2] = f2bf(acc2[m][2] + bv.z);
        o[3] = f2bf(acc2[m][3] + bv.w);
        *(s4v*)(ebuf + (size_t)e * ED + cb) = o;
      }
    }
  }
}

// =======================================================================
// Node kernel: unchanged (R10/R13-benched, 16 waves).
// =======================================================================
__launch_bounds__(1024, 4)
__global__ void node_kernel(const float* __restrict__ x,
                            const short* __restrict__ xbf,
                            const float* __restrict__ u,
                            const short* __restrict__ w3p,
                            const float* __restrict__ b3,
                            const short* __restrict__ w4p,
                            const float* __restrict__ b4,
                            const float* __restrict__ gamma,
                            const float* __restrict__ beta,
                            const int* __restrict__ batch,
                            const unsigned short* __restrict__ aggbf,
                            float* __restrict__ out) {
  __shared__ __align__(16) short smem[64 * 1024];
  const int tid = threadIdx.x;
  const int lane = tid & 63;
  const int w = tid >> 6;
  const int lh = lane >> 4;
  const int ll = lane & 15;
  const int n0 = blockIdx.x * 64;

  #pragma unroll
  for (int it = 0; it < 4; ++it) {
    int ch = tid + it * 1024;
    if (ch < 3584) {
      int rr = ch / 56;
      int cc = (ch - rr * 56) * 8;
      s8v vals = {0, 0, 0, 0, 0, 0, 0, 0};
      int node = n0 + rr;
      if (node < NN) {
        if (cc < 256) {
          vals = *(const s8v*)(xbf + (size_t)node * ND + cc);
        } else if (cc < 384) {
          vals = *(const s8v*)(aggbf + (size_t)node * ED + (cc - 256));
        } else {
          const float* up = u + (size_t)batch[node] * GD + (cc - 384);
          const float4 v0 = *(const float4*)(up);
          const float4 v1 = *(const float4*)(up + 4);
          vals[0] = f2bf(v0.x); vals[1] = f2bf(v0.y); vals[2] = f2bf(v0.z); vals[3] = f2bf(v0.w);
          vals[4] = f2bf(v1.x); vals[5] = f2bf(v1.y); vals[6] = f2bf(v1.z); vals[7] = f2bf(v1.w);
        }
      }
      int byte = (rr * 896 + cc * 2) ^ ((rr & 7) << 4);
      *(s8v*)((char*)smem + byte) = vals;
    }
  }
  __syncthreads();

  f4v acc3[4][4];
  #pragma unroll
  for (int n = 0; n < 4; ++n)
    #pragma unroll
    for (int m = 0; m < 4; ++m)
      acc3[n][m] = (f4v){0.f, 0.f, 0.f, 0.f};

  for (int ks = 0; ks < 14; ++ks) {
    s8v af[4];
    #pragma unroll
    for (int m = 0; m < 4; ++m) {
      int row = 16 * m + ll;
      int byte = (row * 896 + ks * 64 + lh * 16) ^ ((row & 7) << 4);
      af[m] = *(const s8v*)((const char*)smem + byte);
    }
    #pragma unroll
    for (int n = 0; n < 4; ++n) {
      s8v wf = *(const s8v*)(w3p + (((ks * 1024 + w * 64 + 16 * n + ll) * 4 + lh) << 3));
      #pragma unroll
      for (int m = 0; m < 4; ++m)
        acc3[n][m] = __builtin_amdgcn_mfma_f32_16x16x32_bf16(wf, af[m], acc3[n][m], 0, 0, 0);
    }
  }
  __syncthreads();

  #pragma unroll
  for (int n = 0; n < 4; ++n) {
    int cb = w * 64 + 16 * n + 4 * lh;
    const float4 bv = *(const float4*)(b3 + cb);
    #pragma unroll
    for (int m = 0; m < 4; ++m) {
      int row = 16 * m + ll;
      s4v o;
      float v0 = acc3[n][m][0] + bv.x; o[0] = f2bf(v0 > 0.f ? v0 : 0.f);
      float v1 = acc3[n][m][1] + bv.y; o[1] = f2bf(v1 > 0.f ? v1 : 0.f);
      float v2 = acc3[n][m][2] + bv.z; o[2] = f2bf(v2 > 0.f ? v2 : 0.f);
      float v3 = acc3[n][m][3] + bv.w; o[3] = f2bf(v3 > 0.f ? v3 : 0.f);
      int byte = (row * 2048 + cb * 2) ^ ((row & 7) << 4);
      *(s4v*)((char*)smem + byte) = o;
    }
  }
  __syncthreads();

  f4v acc4[4];
  #pragma unroll
  for (int m = 0; m < 4; ++m)
    acc4[m] = (f4v){0.f, 0.f, 0.f, 0.f};

  for (int ks = 0; ks < 32; ++ks) {
    s8v wf = *(const s8v*)(w4p + (((ks * 256 + w * 16 + ll) * 4 + lh) << 3));
    #pragma unroll
    for (int m = 0; m < 4; ++m) {
      int row = 16 * m + ll;
      int byte = (row * 2048 + ks * 64 + lh * 16) ^ ((row & 7) << 4);
      s8v hf = *(const s8v*)((const char*)smem + byte);
      acc4[m] = __builtin_amdgcn_mfma_f32_16x16x32_bf16(wf, hf, acc4[m], 0, 0, 0);
    }
  }
  __syncthreads();

  float* yb = (float*)smem;
  {
    int cb = w * 16 + 4 * lh;
    const float4 bv = *(const float4*)(b4 + cb);
    #pragma unroll
    for (int m = 0; m < 4; ++m) {
      int row = 16 * m + ll;
      int node = n0 + row;
      float4 xv = {0.f, 0.f, 0.f, 0.f};
      if (node < NN) xv = *(const float4*)(x + (size_t)node * ND + cb);
      f4v o;
      o[0] = acc4[m][0] + bv.x + xv.x;
      o[1] = acc4[m][1] + bv.y + xv.y;
      o[2] = acc4[m][2] + bv.z + xv.z;
      o[3] = acc4[m][3] + bv.w + xv.w;
      *(f4v*)(yb + row * 260 + cb) = o;
    }
  }
  __syncthreads();

  {
    int row = tid >> 4, sub = tid & 15;
    int node = n0 + row;
    float v[16];
    float sum = 0.f, ssq = 0.f;
    #pragma unroll
    for (int i = 0; i < 4; ++i) {
      const float4 t = *(const float4*)(yb + row * 260 + (i * 16 + sub) * 4);
      v[i * 4 + 0] = t.x; v[i * 4 + 1] = t.y; v[i * 4 + 2] = t.z; v[i * 4 + 3] = t.w;
      sum += t.x + t.y + t.z + t.w;
      ssq += t.x * t.x + t.y * t.y + t.z * t.z + t.w * t.w;
    }
    #pragma unroll
    for (int d = 1; d < 16; d <<= 1) {
      sum += __shfl_xor(sum, d);
      ssq += __shfl_xor(ssq, d);
    }
    float mu = sum * (1.f / 256.f);
    float var = ssq * (1.f / 256.f) - mu * mu;
    float rstd = rsqrtf(var + 1e-5f);
    if (node < NN) {
      #pragma unroll
      for (int i = 0; i < 4; ++i) {
        int c = (i * 16 + sub) * 4;
        const float4 g = *(const float4*)(gamma + c);
        const float4 be = *(const float4*)(beta + c);
        float4 o;
        o.x = (v[i * 4 + 0] - mu) * rstd * g.x + be.x;
        o.y = (v[i * 4 + 1] - mu) * rstd * g.y + be.y;
        o.z = (v[i * 4 + 2] - mu) * rstd * g.z + be.z;
        o.w = (v[i * 4 + 3] - mu) * rstd * g.w + be.w;
        *(float4*)(out + (size_t)node * ND + c) = o;
      }
    }
  }
}

extern "C" void kernel_launch(void* const* d_in, const int* in_sizes, int n_in,
                              void* d_out, int out_size, void* d_ws, size_t ws_size,
                              hipStream_t stream) {
  const float* x    = (const float*)d_in[0];
  const float* ea   = (const float*)d_in[1];
  const float* u    = (const float*)d_in[2];
  const float* W1   = (const float*)d_in[3];
  const float* b1   = (const float*)d_in[4];
  const float* W2   = (const float*)d_in[5];
  const float* b2   = (const float*)d_in[6];
  const float* W3   = (const float*)d_in[7];
  const float* b3   = (const float*)d_in[8];
  const float* W4   = (const float*)d_in[9];
  const float* b4   = (const float*)d_in[10];
  const float* gamma = (const float*)d_in[11];
  const float* beta  = (const float*)d_in[12];
  const int* eidx   = (const int*)d_in[13];
  const int* batch  = (const int*)d_in[14];
  float* out = (float*)d_out;

  char* p = (char*)d_ws;
  size_t off = 0;
  auto take = [&](size_t n) { char* r = p + off; off = (off + n + 255) & ~(size_t)255; return r; };
  short* xbf = (short*)take((size_t)NN * ND * 2);
  short* w1p = (short*)take((size_t)384 * 512 * 2);
  short* w2p = (short*)take((size_t)512 * 128 * 2);
  short* w3p = (short*)take((size_t)448 * 1024 * 2);
  short* w4p = (short*)take((size_t)1024 * 256 * 2);
  unsigned int* cnt = (unsigned int*)take((size_t)NN * 4);
  int* elist = (int*)take((size_t)NN * MAXDEG * 4);
  unsigned short* aggbf = (unsigned short*)take((size_t)NN * ED * 2);
  unsigned short* ebuf = (unsigned short*)take((size_t)NE * ED * 2);

  const int* erow = eidx;
  const int* ecol = eidx + NE;

  hipMemsetAsync(cnt, 0, (size_t)NN * 4, stream);
  {
    const int total = J0 + J1 + J2 + J3 + J4 + J5;
    prep_kernel<<<(total + 255) / 256, 256, 0, stream>>>(x, xbf, W1, W2, W3, W4,
                                                         w1p, w2p, w3p, w4p,
                                                         ecol, cnt, elist);
  }
  edge_kernel<<<(NE + 127) / 128, 1024, 0, stream>>>(xbf, ea, w1p, b1, w2p, b2, erow, ebuf);
  agg_kernel<<<(NN + 3) / 4, 256, 0, stream>>>(ebuf, elist, cnt, aggbf);
  node_kernel<<<(NN + 63) / 64, 1024, 0, stream>>>(x, xbf, u, w3p, b3, w4p, b4,
                                                   gamma, beta, batch, aggbf, out);
}